// Round 3
// baseline (342.561 us; speedup 1.0000x reference)
//
#include <hip/hip_runtime.h>

#define SEQ    512
#define BATCHN 32768
#define NC     16      // chunks
#define CL     32      // steps per chunk (NC*CL == SEQ)
#define SMINF  0.01f
#define SMAXF  36500.0f

struct __attribute__((aligned(4))) F3 { float x, y, z; };

struct Params {
    float civ0, civ1;          // clip(w0), clip(w1)
    float d0, d1, d2, d3;      // ef delta per rating r: w5 - w3*((r+1)-w4)^2
};

__device__ __forceinline__ Params make_params(const float* __restrict__ wp) {
    Params p;
    const float w0 = wp[0], w1 = wp[1], w3 = wp[3], w4 = wp[4], w5 = wp[5];
    p.civ0 = fminf(fmaxf(w0, SMINF), SMAXF);
    p.civ1 = fminf(fmaxf(w1, SMINF), SMAXF);
    float e0 = 1.0f - w4, e1 = 2.0f - w4, e2 = 3.0f - w4, e3 = 4.0f - w4;
    p.d0 = w5 - w3 * (e0 * e0);
    p.d1 = w5 - w3 * (e1 * e1);
    p.d2 = w5 - w3 * (e2 * e2);
    p.d3 = w5 - w3 * (e3 * e3);
    return p;
}

// One SM-2 step; identical codegen in passes B and C so states agree exactly.
__device__ __forceinline__ void sm2_step(unsigned r, float& ivl, float& ef, float& reps,
                                         const Params& p) {
    const bool succ = r > 1u;
    reps = succ ? (reps + 1.0f) : 1.0f;
    const float prod = fminf(fmaxf(ivl * ef, SMINF), SMAXF);     // uses OLD ef
    ivl = (reps == 1.0f) ? p.civ0 : ((reps == 2.0f) ? p.civ1 : prod);
    const float da = (r & 1u) ? p.d1 : p.d0;
    const float db = (r & 1u) ? p.d3 : p.d2;
    const float dl = (r & 2u) ? db : da;
    ef = fminf(fmaxf(ef + dl, 1.3f), 10.0f);
}

// ---------------------------------------------------------------------------
// Pass A: pack each chunk's 32 ratings (values 0..3) into one uint64 so later
// passes never re-read the 134 MB input. tid = c*BATCHN + b.
// ---------------------------------------------------------------------------
__global__ __launch_bounds__(256) void k_compress(const float* __restrict__ in,
                                                  unsigned long long* __restrict__ rat) {
    const int tid = blockIdx.x * 256 + threadIdx.x;
    const int c = tid >> 15;
    const int b = tid & (BATCHN - 1);
    const float* p = in + (((size_t)(c * CL) * BATCHN + b) * 2 + 1);
    unsigned lo = 0u, hi = 0u;
#pragma unroll
    for (int t = 0; t < CL; ++t) {
        const float r = p[(size_t)t * (2 * BATCHN)];
        const unsigned u = (unsigned)r;
        if (t < 16) lo |= u << (2 * t);
        else        hi |= u << (2 * (t - 16));
    }
    rat[tid] = ((unsigned long long)hi << 32) | lo;
}

// ---------------------------------------------------------------------------
// Pass B: full serial scan of the exact (ivl, ef, reps) recurrence per chain,
// reading only packed ratings (128 B/thread). Emits the concrete state at
// every chunk start, and writes final_state directly.
// ---------------------------------------------------------------------------
__global__ __launch_bounds__(256) void k_scan(const unsigned long long* __restrict__ rat,
                                              const float* __restrict__ wp,
                                              float* __restrict__ ivlS,
                                              float* __restrict__ efS,
                                              float* __restrict__ repsS,
                                              float* __restrict__ out) {
    const int b = blockIdx.x * 256 + threadIdx.x;
    const Params p = make_params(wp);
    float ivl = 0.0f, ef = wp[2], reps = 0.0f;
    unsigned long long wcur = rat[b];
#pragma unroll 1
    for (int c = 0; c < NC; ++c) {
        unsigned long long wnext = 0ull;
        if (c + 1 < NC) wnext = rat[(c + 1) * BATCHN + b];   // prefetch next chunk
        ivlS[c * BATCHN + b]  = ivl;
        efS[c * BATCHN + b]   = ef;
        repsS[c * BATCHN + b] = reps;
        const unsigned lo = (unsigned)wcur, hi = (unsigned)(wcur >> 32);
#pragma unroll
        for (int t = 0; t < CL; ++t) {
            const unsigned r = ((t < 16 ? lo : hi) >> ((2 * t) & 31)) & 3u;
            sm2_step(r, ivl, ef, reps, p);
        }
        wcur = wnext;
    }
    F3 fs; fs.x = ivl; fs.y = ef; fs.z = reps;
    *((F3*)(out + (size_t)SEQ * BATCHN * 3) + b) = fs;       // final_state
}

// ---------------------------------------------------------------------------
// Pass C: branch-free concrete replay of one chunk per thread; writes all
// outputs as one 12 B (dwordx3) store per step — a wave's 64 lanes cover
// 768 contiguous bytes per instruction.
// ---------------------------------------------------------------------------
__global__ __launch_bounds__(256) void k_emit(const unsigned long long* __restrict__ rat,
                                              const float* __restrict__ wp,
                                              const float* __restrict__ ivlS,
                                              const float* __restrict__ efS,
                                              const float* __restrict__ repsS,
                                              float* __restrict__ out) {
    const int tid = blockIdx.x * 256 + threadIdx.x;   // tid = c*BATCHN + b
    const int c = tid >> 15;
    const int b = tid & (BATCHN - 1);
    const Params p = make_params(wp);
    float ivl  = ivlS[tid];
    float ef   = efS[tid];
    float reps = repsS[tid];
    const unsigned long long w = rat[tid];
    const unsigned lo = (unsigned)w, hi = (unsigned)(w >> 32);
    F3* o = (F3*)out + ((size_t)(c * CL) * BATCHN + b);
#pragma unroll
    for (int t = 0; t < CL; ++t) {
        const unsigned r = ((t < 16 ? lo : hi) >> ((2 * t) & 31)) & 3u;
        sm2_step(r, ivl, ef, reps, p);
        F3 v; v.x = ivl; v.y = ef; v.z = reps;
        *o = v;
        o += BATCHN;
    }
}

extern "C" void kernel_launch(void* const* d_in, const int* in_sizes, int n_in,
                              void* d_out, int out_size, void* d_ws, size_t ws_size,
                              hipStream_t stream) {
    const float* in = (const float*)d_in[0];
    const float* w  = (const float*)d_in[1];
    float* out      = (float*)d_out;
    char* ws        = (char*)d_ws;

    // ws layout (10.5 MB):
    unsigned long long* rat = (unsigned long long*)(ws);    // 16*32768*8 = 4,194,304 B
    float* ivlS  = (float*)(ws + 4194304);                  // 2,097,152 B
    float* efS   = (float*)(ws + 6291456);                  // 2,097,152 B
    float* repsS = (float*)(ws + 8388608);                  // 2,097,152 B

    k_compress<<<NC * BATCHN / 256, 256, 0, stream>>>(in, rat);
    k_scan    <<<BATCHN / 256,      256, 0, stream>>>(rat, w, ivlS, efS, repsS, out);
    k_emit    <<<NC * BATCHN / 256, 256, 0, stream>>>(rat, w, ivlS, efS, repsS, out);
}